// Round 14
// baseline (177.443 us; speedup 1.0000x reference)
//
#include <hip/hip_runtime.h>
#include <hip/hip_bf16.h>

constexpr int kN = 8192;
constexpr int kD = 128;
constexpr int JSPLIT = 4;   // j strips; grid = (kN/16) x 4 = 2048 blocks
constexpr int TB = 64;      // rowsum tile
constexpr int NB = kN / TB; // 128

typedef __bf16 v8bf __attribute__((ext_vector_type(8)));
typedef float  v4f  __attribute__((ext_vector_type(4)));

// K_raw with 3 transcendentals (round-8 proven).
__device__ __forceinline__ float kraw_f(float4 ci, float sqi, float4 cj, float sqj) {
    float d2 = sqi + sqj - 2.0f * (ci.x * cj.x + ci.y * cj.y + ci.z * cj.z);
    d2 = fmaxf(d2, 1e-12f);
    float Dd = __builtin_amdgcn_sqrtf(d2);
    float a = 0.5f * (ci.w + cj.w);
    float t = a * (-0.5f * __builtin_amdgcn_logf(d2));                // -a*log2(D)
    t = fminf(fmaxf(t, -26.575424759098897f), 9.965784284662087f);   // log2(1e-8), log2(1000)
    float K = __builtin_amdgcn_exp2f(fmaf(Dd, -0.12022458674074695f, t));
    return fminf(K, 1000.0f);  // K >= 0 always
}

// --- kernel 1: pack coords+alpha into float4 (proven) ----------------------
__global__ void pack_k(const float* __restrict__ coords, const float* __restrict__ alpha,
                       float4* __restrict__ c4) {
    int j = blockIdx.x * 256 + threadIdx.x;
    if (j < kN) {
        c4[j] = make_float4(coords[3 * j], coords[3 * j + 1], coords[3 * j + 2], alpha[j]);
    }
}

// --- kernel 2: fragment-native B prep --------------------------------------
// latTf layout: for global 32-col window jw (0..255) and d-tile d (0..8):
// a contiguous 1KB block = the exact 64-lane x 16B MFMA B-fragment:
//   lane l holds latent[jw*32 + (l>>4)*8 + e][d*16 + (l&15)], e=0..7, bf16.
// main_k's B-load is then ONE coalesced dwordx4 per d-tile.
__global__ __launch_bounds__(256) void fragprep_k(const float* __restrict__ latent,
                                                  __bf16* __restrict__ latTf) {
    __shared__ float ltile[32][132];   // 32 j-rows x 128 dims (pad 4)
    const int jw = blockIdx.x;
    const int t = threadIdx.x;

    #pragma unroll
    for (int it = 0; it < 4; ++it) {
        int idx = it * 256 + t;            // 0..1023
        int row = idx >> 5;                // 0..31
        int col = (idx & 31) * 4;          // 0..124
        float4 v = *reinterpret_cast<const float4*>(
            latent + (size_t)(jw * 32 + row) * kD + col);
        *reinterpret_cast<float4*>(&ltile[row][col]) = v;
    }
    __syncthreads();

    #pragma unroll
    for (int ss = 0; ss < 2; ++ss) {
        int s = ss * 256 + t;              // 0..511 fragment slots
        int d = s >> 6, l = s & 63;
        int jr = (l >> 4) * 8, dim = d * 16 + (l & 15);
        unsigned w[4];
        #pragma unroll
        for (int e2 = 0; e2 < 4; ++e2) {
            __bf16 lo = (__bf16)ltile[jr + 2 * e2][dim];
            __bf16 hi = (__bf16)ltile[jr + 2 * e2 + 1][dim];
            w[e2] = ((unsigned)*(unsigned short*)&hi << 16) | *(unsigned short*)&lo;
        }
        uint4 out = {w[0], w[1], w[2], w[3]};
        *reinterpret_cast<uint4*>((char*)latTf + (((size_t)jw * 8 + d) * 64 + l) * 16) = out;
    }
}

// --- kernel 3: SYMMETRIC row sums (round-11 proven) ------------------------
__global__ __launch_bounds__(256) void rowsum_sym_k(const float4* __restrict__ c4,
                                                    float* __restrict__ rsum) {
    __shared__ float4 rc4[TB];
    __shared__ float  rsq[TB];
    __shared__ float  rowbuf[TB][TB + 1];   // 16.25 KB

    // decode triangular pair (bi <= bj) from linear block index
    int L = blockIdx.x;
    int bi = (int)((2 * NB + 1 - sqrtf((float)((2 * NB + 1) * (2 * NB + 1) - 8 * L))) * 0.5f);
    #pragma unroll
    for (int f = 0; f < 2; ++f) {
        int s0 = bi * NB - bi * (bi - 1) / 2;
        int s1 = (bi + 1) * NB - (bi + 1) * bi / 2;
        if (L >= s1) ++bi;
        else if (L < s0) --bi;
    }
    int sbi = bi * NB - bi * (bi - 1) / 2;
    int bj = bi + (L - sbi);
    bool diag = (bi == bj);

    const int t = threadIdx.x;
    const int l = t & 63;
    const int w = t >> 6;

    if (t < TB) {
        float4 ci = c4[bi * TB + t];
        rc4[t] = ci;
        rsq[t] = ci.x * ci.x + ci.y * ci.y + ci.z * ci.z;
    }
    __syncthreads();

    float4 cj = c4[bj * TB + l];
    float sqj = cj.x * cj.x + cj.y * cj.y + cj.z * cj.z;

    float colacc = 0.f;
    #pragma unroll
    for (int rr = 0; rr < 16; ++rr) {
        int r = w * 16 + rr;
        float k = kraw_f(rc4[r], rsq[r], cj, sqj);
        if (diag && r == l) k = 0.f;
        colacc += k;
        rowbuf[r][l] = k;
    }
    __syncthreads();

    // row sums: thread t -> row r = t>>2, quarter q = t&3 (adjacent lanes)
    {
        int r = t >> 2, q = t & 3;
        float p = 0.f;
        #pragma unroll
        for (int m = 0; m < 16; ++m) p += rowbuf[r][q * 16 + m];
        p += __shfl_xor(p, 1, 64);
        p += __shfl_xor(p, 2, 64);
        if (q == 0) atomicAdd(&rsum[bi * TB + r], p);
    }
    if (!diag) atomicAdd(&rsum[bj * TB + l], colacc);
}

// --- kernel 4: fused K write + MFMA GEMM — BARRIER-FREE, ZERO-LDS ----------
// Block = 4 independent waves. Block owns 16 output rows; wave w owns the
// 512-col sub-strip w of the block's 2048-col strip, in 32-col windows.
// Thread = its MFMA A-fragment (row = lane&15, cols jc..jc+8): 8 kraw ->
// two v4f Kout stores -> bf16 a-frag (r4-proven). B-fragment = ONE coalesced
// 16B load per d-tile from fragment-native latTf (L2-resident). acc[8].
// Epilogue: r4/r6-proven direct atomicAdd (16 writers per element).
__global__ __launch_bounds__(256) void main_k(
    const float4* __restrict__ c4, const float* __restrict__ rsum,
    const __bf16* __restrict__ latTf, float* __restrict__ outp,
    float* __restrict__ Kout) {

    const int t = threadIdx.x;
    const int lane = t & 63;
    const int wave = t >> 6;
    const int i0 = blockIdx.x * 16;
    const int r = lane & 15;               // A row owned by this thread
    const int slot = lane >> 4;            // 0..3
    const int koff = slot * 8;
    const int gi = i0 + r;

    const float4 ci = c4[gi];
    const float sqi = ci.x * ci.x + ci.y * ci.y + ci.z * ci.z;
    const float inv_i = 1.0f / (rsum[gi] + 1e-8f);

    const int jbase = blockIdx.y * (kN / JSPLIT) + wave * (kN / JSPLIT / 4);
    constexpr int NIT = kN / JSPLIT / 4 / 32;   // 16 windows per wave

    v4f acc[8];
    #pragma unroll
    for (int d = 0; d < 8; ++d) acc[d] = (v4f){0.f, 0.f, 0.f, 0.f};

    for (int cb = 0; cb < NIT; ++cb) {
        const int j0w = jbase + cb * 32;
        const int jc = j0w + koff;          // first of this thread's 8 columns

        float kn[8];
        #pragma unroll
        for (int e = 0; e < 8; ++e) {
            float4 cj = c4[jc + e];
            float sqj = cj.x * cj.x + cj.y * cj.y + cj.z * cj.z;
            float k = (gi == jc + e) ? 0.0f : kraw_f(ci, sqi, cj, sqj);
            kn[e] = k * inv_i;
        }

        // K output: two 16B stores; lanes {r,r+16,r+32,r+48} tile 128B per row
        float* kp = Kout + (size_t)gi * kN + jc;
        v4f s0 = {kn[0], kn[1], kn[2], kn[3]};
        v4f s1 = {kn[4], kn[5], kn[6], kn[7]};
        *reinterpret_cast<v4f*>(kp)     = s0;
        *reinterpret_cast<v4f*>(kp + 4) = s1;

        v8bf a;
        #pragma unroll
        for (int e = 0; e < 8; ++e) a[e] = (__bf16)kn[e];

        // B: one coalesced 1KB fragment per d-tile from latTf
        const int jw = j0w >> 5;            // global window index
        const char* bbase = (const char*)latTf + (((size_t)jw * 8) * 64 + lane) * 16;
        #pragma unroll
        for (int d = 0; d < 8; ++d) {
            v8bf b = *reinterpret_cast<const v8bf*>(bbase + d * 1024);
            acc[d] = __builtin_amdgcn_mfma_f32_16x16x32_bf16(a, b, acc[d], 0, 0, 0);
        }
    }

    // epilogue: C/D frag col = lane&15, row = (lane>>4)*4 + q  [m89, r4-proven]
    const int row = slot * 4;
    #pragma unroll
    for (int d = 0; d < 8; ++d)
        #pragma unroll
        for (int q = 0; q < 4; ++q)
            atomicAdd(&outp[(size_t)(i0 + row + q) * kD + d * 16 + r], acc[d][q]);
}

extern "C" void kernel_launch(void* const* d_in, const int* in_sizes, int n_in,
                              void* d_out, int out_size, void* d_ws, size_t ws_size,
                              hipStream_t stream) {
    const float* latent = (const float*)d_in[0];
    const float* coords = (const float*)d_in[1];
    const float* alpha  = (const float*)d_in[2];

    float* outp = (float*)d_out;                    // [8192][128]
    float* Kout = (float*)d_out + (size_t)kN * kD;  // [8192][8192]

    // ws layout: byte-identical footprint to the proven one.
    char* ws = (char*)d_ws;
    __bf16* latTf = (__bf16*)ws;                                  // 2 MiB
    float4* c4    = (float4*)(ws + 2u * 1024 * 1024);             // 128 KiB
    float*  rsum  = (float*)(ws + 2u * 1024 * 1024 + 128 * 1024); // 32 KiB

    hipMemsetAsync(outp, 0, (size_t)kN * kD * sizeof(float), stream);
    hipMemsetAsync(rsum, 0, kN * sizeof(float), stream);

    pack_k<<<dim3(kN / 256), dim3(256), 0, stream>>>(coords, alpha, c4);
    fragprep_k<<<dim3(kN / 32), dim3(256), 0, stream>>>(latent, latTf);
    rowsum_sym_k<<<dim3(NB * (NB + 1) / 2), dim3(256), 0, stream>>>(c4, rsum);
    main_k<<<dim3(kN / 16, JSPLIT), dim3(256), 0, stream>>>(c4, rsum, latTf, outp, Kout);
}

// Round 16
// 142.551 us; speedup vs baseline: 1.2448x; 1.2448x over previous
//
#include <hip/hip_runtime.h>
#include <hip/hip_bf16.h>

constexpr int kN = 8192;
constexpr int kD = 128;
constexpr int BM = 32;      // rows per block in main kernel (2 MFMA row-tiles)
constexpr int BK = 64;      // j-chunk
constexpr int JSPLIT = 8;   // j-range strips (grid at 2048 blocks)
constexpr int LDB = 66;     // A-tile LDS row stride: 132B (r9-proven, conflict-free)
constexpr int TB = 64;      // rowsum tile
constexpr int NB = kN / TB; // 128

typedef __bf16 v8bf __attribute__((ext_vector_type(8)));
typedef float  v4f  __attribute__((ext_vector_type(4)));
typedef float  v2f  __attribute__((ext_vector_type(2)));

// async global->LDS, 16B per lane (r10-proven).
__device__ __forceinline__ void gload16(const void* g, void* l) {
    __builtin_amdgcn_global_load_lds(
        (const __attribute__((address_space(1))) void*)g,
        (__attribute__((address_space(3))) void*)l, 16, 0, 0);
}

// K_raw with 3 transcendentals (round-8 proven).
__device__ __forceinline__ float kraw_f(float4 ci, float sqi, float4 cj, float sqj) {
    float d2 = sqi + sqj - 2.0f * (ci.x * cj.x + ci.y * cj.y + ci.z * cj.z);
    d2 = fmaxf(d2, 1e-12f);
    float Dd = __builtin_amdgcn_sqrtf(d2);
    float a = 0.5f * (ci.w + cj.w);
    float t = a * (-0.5f * __builtin_amdgcn_logf(d2));                // -a*log2(D)
    t = fminf(fmaxf(t, -26.575424759098897f), 9.965784284662087f);   // log2(1e-8), log2(1000)
    float K = __builtin_amdgcn_exp2f(fmaf(Dd, -0.12022458674074695f, t));
    return fminf(K, 1000.0f);  // K >= 0 always
}

// --- kernel 1: pack coords+alpha into float4 (proven) ----------------------
__global__ void pack_k(const float* __restrict__ coords, const float* __restrict__ alpha,
                       float4* __restrict__ c4) {
    int j = blockIdx.x * 256 + threadIdx.x;
    if (j < kN) {
        c4[j] = make_float4(coords[3 * j], coords[3 * j + 1], coords[3 * j + 2], alpha[j]);
    }
}

// --- kernel 2: transpose latent [N][128] f32 -> latT [128][N] bf16 (proven) -
__global__ void transpose_k(const float* __restrict__ latent, __bf16* __restrict__ latT) {
    __shared__ float tile[32][33];
    int t = threadIdx.x;
    int tx = t & 31, ty = t >> 5;          // 32 x 8
    int j0 = blockIdx.x * 32, d0 = blockIdx.y * 32;
    #pragma unroll
    for (int i = 0; i < 32; i += 8)
        tile[ty + i][tx] = latent[(size_t)(j0 + ty + i) * kD + d0 + tx];
    __syncthreads();
    #pragma unroll
    for (int i = 0; i < 32; i += 8)
        latT[(size_t)(d0 + ty + i) * kN + j0 + tx] = (__bf16)tile[tx][ty + i];
}

// --- kernel 3: SYMMETRIC row sums (round-11 proven) ------------------------
__global__ __launch_bounds__(256) void rowsum_sym_k(const float4* __restrict__ c4,
                                                    float* __restrict__ rsum) {
    __shared__ float4 rc4[TB];
    __shared__ float  rsq[TB];
    __shared__ float  rowbuf[TB][TB + 1];   // 16.25 KB

    // decode triangular pair (bi <= bj) from linear block index
    int L = blockIdx.x;
    int bi = (int)((2 * NB + 1 - sqrtf((float)((2 * NB + 1) * (2 * NB + 1) - 8 * L))) * 0.5f);
    #pragma unroll
    for (int f = 0; f < 2; ++f) {
        int s0 = bi * NB - bi * (bi - 1) / 2;
        int s1 = (bi + 1) * NB - (bi + 1) * bi / 2;
        if (L >= s1) ++bi;
        else if (L < s0) --bi;
    }
    int sbi = bi * NB - bi * (bi - 1) / 2;
    int bj = bi + (L - sbi);
    bool diag = (bi == bj);

    const int t = threadIdx.x;
    const int l = t & 63;
    const int w = t >> 6;

    if (t < TB) {
        float4 ci = c4[bi * TB + t];
        rc4[t] = ci;
        rsq[t] = ci.x * ci.x + ci.y * ci.y + ci.z * ci.z;
    }
    __syncthreads();

    float4 cj = c4[bj * TB + l];
    float sqj = cj.x * cj.x + cj.y * cj.y + cj.z * cj.z;

    float colacc = 0.f;
    #pragma unroll
    for (int rr = 0; rr < 16; ++rr) {
        int r = w * 16 + rr;
        float k = kraw_f(rc4[r], rsq[r], cj, sqj);
        if (diag && r == l) k = 0.f;
        colacc += k;
        rowbuf[r][l] = k;
    }
    __syncthreads();

    // row sums: thread t -> row r = t>>2, quarter q = t&3 (adjacent lanes)
    {
        int r = t >> 2, q = t & 3;
        float p = 0.f;
        #pragma unroll
        for (int m = 0; m < 16; ++m) p += rowbuf[r][q * 16 + m];
        p += __shfl_xor(p, 1, 64);
        p += __shfl_xor(p, 2, 64);
        if (q == 0) atomicAdd(&rsum[bi * TB + r], p);
    }
    if (!diag) atomicAdd(&rsum[bj * TB + l], colacc);
}

// --- kernel 4: fused K write + MFMA GEMM (round-11 EXACT + nt Kout stores) -
__global__ __launch_bounds__(256, 2) void main_k(
    const float4* __restrict__ c4, const float* __restrict__ rsum,
    const __bf16* __restrict__ latT, float* __restrict__ outp, float* __restrict__ Kout) {

    __shared__ __bf16 Alds[BM][LDB];    // 4.2 KB, normalized K tile
    __shared__ __bf16 Blin[kD * BK];    // 16 KB, swizzled physical layout
    __shared__ float4 c4row[BM];
    __shared__ float  sqrow[BM];
    __shared__ float  invrow[BM];

    const int t = threadIdx.x;
    const int i0 = blockIdx.x * BM;
    const int jstrip = blockIdx.y * (kN / JSPLIT);

    if (t < BM) {
        float4 ci = c4[i0 + t];
        c4row[t] = ci;
        sqrow[t] = ci.x * ci.x + ci.y * ci.y + ci.z * ci.z;
        invrow[t] = 1.0f / (rsum[i0 + t] + 1e-8f);
    }
    __syncthreads();

    const int lane = t & 63;
    const int wave = t >> 6;

    // K-tile compute mapping: col pair {2*c2, 2*c2+1}, rows rb..rb+3
    const int c2 = t & 31;
    const int rb = (t >> 5) * 4;

    // hoist this thread's 4 fixed rows into registers (r11-proven)
    float4 rc[4]; float rs[4], rv[4];
    #pragma unroll
    for (int rr = 0; rr < 4; ++rr) {
        rc[rr] = c4row[rb + rr];
        rs[rr] = sqrow[rb + rr];
        rv[rr] = invrow[rb + rr];
    }

    // MFMA fragment addressing (r9/r10-proven)
    const int arow = lane & 15;
    const int koff = (lane >> 4) * 8;          // elements
    const int dbase = wave * 32;
    const int bswz = ((dbase + arow) & 7) << 4; // source/read XOR (involution)

    // staging: dest byte = it*4096 + t*16 -> (row = it*32 + t/8, col-byte =
    // (t&7)*16); source col-byte pre-swizzled by ^((row&7)<<4)
    const int srow = t >> 3;
    const int scolb = ((t & 7) ^ (srow & 7)) << 4;

    v4f acc[2][2];
    #pragma unroll
    for (int rt = 0; rt < 2; ++rt)
        #pragma unroll
        for (int dt = 0; dt < 2; ++dt) acc[rt][dt] = (v4f){0.f, 0.f, 0.f, 0.f};

    for (int cb = 0; cb < kN / JSPLIT / BK; ++cb) {
        const int j0 = jstrip + cb * BK;

        // issue async B staging first (flies under the kraw compute)
        #pragma unroll
        for (int it = 0; it < 4; ++it) {
            int row = it * 32 + srow;
            const char* src = (const char*)latT + ((size_t)row * kN + j0) * 2 + scolb;
            char* dst = (char*)Blin + it * 4096 + t * 16;
            gload16(src, dst);
        }

        // K tile (32 x 64): cols {gjA, gjB}, rows rb..rb+3; kraw once per elem
        const int gjA = j0 + 2 * c2, gjB = gjA + 1;
        const float4 cjA = c4[gjA];
        const float4 cjB = c4[gjB];
        const float sqA = cjA.x * cjA.x + cjA.y * cjA.y + cjA.z * cjA.z;
        const float sqB = cjB.x * cjB.x + cjB.y * cjB.y + cjB.z * cjB.z;
        #pragma unroll
        for (int rr = 0; rr < 4; ++rr) {
            int r = rb + rr, gi = i0 + r;
            float kA = (gi == gjA) ? 0.0f : kraw_f(rc[rr], rs[rr], cjA, sqA);
            float kB = (gi == gjB) ? 0.0f : kraw_f(rc[rr], rs[rr], cjB, sqB);
            float knA = kA * rv[rr];
            float knB = kB * rv[rr];
            v2f st = {knA, knB};
            // NONTEMPORAL: K is stream-once; keep it out of L2 so latT/c4
            // stay resident and eviction pressure vanishes.
            __builtin_nontemporal_store(st,
                reinterpret_cast<v2f*>(Kout + (size_t)gi * kN + gjA));
            __bf16 hA = (__bf16)knA, hB = (__bf16)knB;
            unsigned pk = ((unsigned)*(unsigned short*)&hB << 16) | *(unsigned short*)&hA;
            *reinterpret_cast<unsigned*>(&Alds[r][2 * c2]) = pk;
        }
        __syncthreads();

        // MFMA: A row-tiles {0,1} x B dim-tiles {0,1}
        #pragma unroll
        for (int kk = 0; kk < 2; ++kk) {
            v8bf a0 = *reinterpret_cast<const v8bf*>(&Alds[arow][kk * 32 + koff]);
            v8bf a1 = *reinterpret_cast<const v8bf*>(&Alds[16 + arow][kk * 32 + koff]);
            const int bc = kk * 64 + koff * 2;    // logical byte col
            const char* bp0 = (const char*)Blin + (dbase + arow) * 128 + (bc ^ bswz);
            const char* bp1 = (const char*)Blin + (dbase + 16 + arow) * 128 + (bc ^ bswz);
            v8bf b0 = *reinterpret_cast<const v8bf*>(bp0);
            v8bf b1 = *reinterpret_cast<const v8bf*>(bp1);
            acc[0][0] = __builtin_amdgcn_mfma_f32_16x16x32_bf16(a0, b0, acc[0][0], 0, 0, 0);
            acc[0][1] = __builtin_amdgcn_mfma_f32_16x16x32_bf16(a0, b1, acc[0][1], 0, 0, 0);
            acc[1][0] = __builtin_amdgcn_mfma_f32_16x16x32_bf16(a1, b0, acc[1][0], 0, 0, 0);
            acc[1][1] = __builtin_amdgcn_mfma_f32_16x16x32_bf16(a1, b1, acc[1][1], 0, 0, 0);
        }
        __syncthreads();
    }

    // epilogue: D frag col = lane&15 (dim), row = (lane>>4)*4 + q  [m89 proven]
    const int row = (lane >> 4) * 4;
    const int col0 = wave * 32 + (lane & 15);
    #pragma unroll
    for (int rt = 0; rt < 2; ++rt)
        #pragma unroll
        for (int dt = 0; dt < 2; ++dt)
            #pragma unroll
            for (int q = 0; q < 4; ++q)
                atomicAdd(&outp[(size_t)(i0 + rt * 16 + row + q) * kD + col0 + dt * 16],
                          acc[rt][dt][q]);
}

extern "C" void kernel_launch(void* const* d_in, const int* in_sizes, int n_in,
                              void* d_out, int out_size, void* d_ws, size_t ws_size,
                              hipStream_t stream) {
    const float* latent = (const float*)d_in[0];
    const float* coords = (const float*)d_in[1];
    const float* alpha  = (const float*)d_in[2];

    float* outp = (float*)d_out;                    // [8192][128]
    float* Kout = (float*)d_out + (size_t)kN * kD;  // [8192][8192]

    // ws layout: byte-identical to the proven footprint.
    char* ws = (char*)d_ws;
    __bf16* latT = (__bf16*)ws;                                   // 2 MiB
    float4* c4   = (float4*)(ws + 2u * 1024 * 1024);              // 128 KiB
    float*  rsum = (float*)(ws + 2u * 1024 * 1024 + 128 * 1024);  // 32 KiB

    hipMemsetAsync(outp, 0, (size_t)kN * kD * sizeof(float), stream);
    hipMemsetAsync(rsum, 0, kN * sizeof(float), stream);

    pack_k<<<dim3(kN / 256), dim3(256), 0, stream>>>(coords, alpha, c4);
    transpose_k<<<dim3(kN / 32, kD / 32), dim3(256), 0, stream>>>(latent, latT);
    rowsum_sym_k<<<dim3(NB * (NB + 1) / 2), dim3(256), 0, stream>>>(c4, rsum);
    main_k<<<dim3(kN / BM, JSPLIT), dim3(256), 0, stream>>>(c4, rsum, latT, outp, Kout);
}

// Round 17
// 125.394 us; speedup vs baseline: 1.4151x; 1.1368x over previous
//
#include <hip/hip_runtime.h>
#include <hip/hip_bf16.h>

constexpr int kN = 8192;
constexpr int kD = 128;
constexpr int BM = 32;      // rows per block in main kernel (2 MFMA row-tiles)
constexpr int BK = 64;      // j-chunk
constexpr int JSPLIT = 8;   // j-range strips (grid at 2048 blocks)
constexpr int LDB = 66;     // A-tile LDS row stride: 132B (r9-proven, conflict-free)
constexpr int TB = 64;      // rowsum tile
constexpr int NB = kN / TB; // 128

typedef __bf16 v8bf __attribute__((ext_vector_type(8)));
typedef float  v4f  __attribute__((ext_vector_type(4)));

// async global->LDS, 16B per lane (r10-proven).
__device__ __forceinline__ void gload16(const void* g, void* l) {
    __builtin_amdgcn_global_load_lds(
        (const __attribute__((address_space(1))) void*)g,
        (__attribute__((address_space(3))) void*)l, 16, 0, 0);
}

// K_raw with 3 transcendentals (round-8 proven).
__device__ __forceinline__ float kraw_f(float4 ci, float sqi, float4 cj, float sqj) {
    float d2 = sqi + sqj - 2.0f * (ci.x * cj.x + ci.y * cj.y + ci.z * cj.z);
    d2 = fmaxf(d2, 1e-12f);
    float Dd = __builtin_amdgcn_sqrtf(d2);
    float a = 0.5f * (ci.w + cj.w);
    float t = a * (-0.5f * __builtin_amdgcn_logf(d2));                // -a*log2(D)
    t = fminf(fmaxf(t, -26.575424759098897f), 9.965784284662087f);   // log2(1e-8), log2(1000)
    float K = __builtin_amdgcn_exp2f(fmaf(Dd, -0.12022458674074695f, t));
    return fminf(K, 1000.0f);  // K >= 0 always
}

// --- kernel 1: pack coords+alpha into float4 (proven) ----------------------
__global__ void pack_k(const float* __restrict__ coords, const float* __restrict__ alpha,
                       float4* __restrict__ c4) {
    int j = blockIdx.x * 256 + threadIdx.x;
    if (j < kN) {
        c4[j] = make_float4(coords[3 * j], coords[3 * j + 1], coords[3 * j + 2], alpha[j]);
    }
}

// --- kernel 2: transpose latent [N][128] f32 -> latT [128][N] bf16 (proven) -
__global__ void transpose_k(const float* __restrict__ latent, __bf16* __restrict__ latT) {
    __shared__ float tile[32][33];
    int t = threadIdx.x;
    int tx = t & 31, ty = t >> 5;          // 32 x 8
    int j0 = blockIdx.x * 32, d0 = blockIdx.y * 32;
    #pragma unroll
    for (int i = 0; i < 32; i += 8)
        tile[ty + i][tx] = latent[(size_t)(j0 + ty + i) * kD + d0 + tx];
    __syncthreads();
    #pragma unroll
    for (int i = 0; i < 32; i += 8)
        latT[(size_t)(d0 + ty + i) * kN + j0 + tx] = (__bf16)tile[tx][ty + i];
}

// --- kernel 3: SYMMETRIC row sums (round-11 proven) ------------------------
__global__ __launch_bounds__(256) void rowsum_sym_k(const float4* __restrict__ c4,
                                                    float* __restrict__ rsum) {
    __shared__ float4 rc4[TB];
    __shared__ float  rsq[TB];
    __shared__ float  rowbuf[TB][TB + 1];   // 16.25 KB

    // decode triangular pair (bi <= bj) from linear block index
    int L = blockIdx.x;
    int bi = (int)((2 * NB + 1 - sqrtf((float)((2 * NB + 1) * (2 * NB + 1) - 8 * L))) * 0.5f);
    #pragma unroll
    for (int f = 0; f < 2; ++f) {
        int s0 = bi * NB - bi * (bi - 1) / 2;
        int s1 = (bi + 1) * NB - (bi + 1) * bi / 2;
        if (L >= s1) ++bi;
        else if (L < s0) --bi;
    }
    int sbi = bi * NB - bi * (bi - 1) / 2;
    int bj = bi + (L - sbi);
    bool diag = (bi == bj);

    const int t = threadIdx.x;
    const int l = t & 63;
    const int w = t >> 6;

    if (t < TB) {
        float4 ci = c4[bi * TB + t];
        rc4[t] = ci;
        rsq[t] = ci.x * ci.x + ci.y * ci.y + ci.z * ci.z;
    }
    __syncthreads();

    float4 cj = c4[bj * TB + l];
    float sqj = cj.x * cj.x + cj.y * cj.y + cj.z * cj.z;

    float colacc = 0.f;
    #pragma unroll
    for (int rr = 0; rr < 16; ++rr) {
        int r = w * 16 + rr;
        float k = kraw_f(rc4[r], rsq[r], cj, sqj);
        if (diag && r == l) k = 0.f;
        colacc += k;
        rowbuf[r][l] = k;
    }
    __syncthreads();

    // row sums: thread t -> row r = t>>2, quarter q = t&3 (adjacent lanes)
    {
        int r = t >> 2, q = t & 3;
        float p = 0.f;
        #pragma unroll
        for (int m = 0; m < 16; ++m) p += rowbuf[r][q * 16 + m];
        p += __shfl_xor(p, 1, 64);
        p += __shfl_xor(p, 2, 64);
        if (q == 0) atomicAdd(&rsum[bi * TB + r], p);
    }
    if (!diag) atomicAdd(&rsum[bj * TB + l], colacc);
}

// --- kernel 4: fused K write + MFMA GEMM (round-11 EXACT + counted waits) --
// Identical to the 123.8 µs r11 kernel except the two loop barriers:
// b1: s_waitcnt vmcnt(4) lgkmcnt(0) — staging gloads (older than >=6 younger
//     vmem ops) and A ds_writes are visible; this iter's 4 Kout stores may
//     stay in flight across the barrier (drain during the MFMA phase).
// b2: s_waitcnt lgkmcnt(0) only — protects Alds/Blin reuse (ds_reads done);
//     no vmem constraint.
__global__ __launch_bounds__(256, 2) void main_k(
    const float4* __restrict__ c4, const float* __restrict__ rsum,
    const __bf16* __restrict__ latT, float* __restrict__ outp, float* __restrict__ Kout) {

    __shared__ __bf16 Alds[BM][LDB];    // 4.2 KB, normalized K tile
    __shared__ __bf16 Blin[kD * BK];    // 16 KB, swizzled physical layout
    __shared__ float4 c4row[BM];
    __shared__ float  sqrow[BM];
    __shared__ float  invrow[BM];

    const int t = threadIdx.x;
    const int i0 = blockIdx.x * BM;
    const int jstrip = blockIdx.y * (kN / JSPLIT);

    if (t < BM) {
        float4 ci = c4[i0 + t];
        c4row[t] = ci;
        sqrow[t] = ci.x * ci.x + ci.y * ci.y + ci.z * ci.z;
        invrow[t] = 1.0f / (rsum[i0 + t] + 1e-8f);
    }
    __syncthreads();

    const int lane = t & 63;
    const int wave = t >> 6;

    // K-tile compute mapping: col pair {2*c2, 2*c2+1}, rows rb..rb+3
    const int c2 = t & 31;
    const int rb = (t >> 5) * 4;

    // hoist this thread's 4 fixed rows into registers (r11-proven)
    float4 rc[4]; float rs[4], rv[4];
    #pragma unroll
    for (int rr = 0; rr < 4; ++rr) {
        rc[rr] = c4row[rb + rr];
        rs[rr] = sqrow[rb + rr];
        rv[rr] = invrow[rb + rr];
    }

    // MFMA fragment addressing (r9/r10-proven)
    const int arow = lane & 15;
    const int koff = (lane >> 4) * 8;          // elements
    const int dbase = wave * 32;
    const int bswz = ((dbase + arow) & 7) << 4; // source/read XOR (involution)

    // staging: dest byte = it*4096 + t*16 -> (row = it*32 + t/8, col-byte =
    // (t&7)*16); source col-byte pre-swizzled by ^((row&7)<<4)
    const int srow = t >> 3;
    const int scolb = ((t & 7) ^ (srow & 7)) << 4;

    v4f acc[2][2];
    #pragma unroll
    for (int rt = 0; rt < 2; ++rt)
        #pragma unroll
        for (int dt = 0; dt < 2; ++dt) acc[rt][dt] = (v4f){0.f, 0.f, 0.f, 0.f};

    for (int cb = 0; cb < kN / JSPLIT / BK; ++cb) {
        const int j0 = jstrip + cb * BK;

        // issue async B staging first (flies under the kraw compute)
        #pragma unroll
        for (int it = 0; it < 4; ++it) {
            int row = it * 32 + srow;
            const char* src = (const char*)latT + ((size_t)row * kN + j0) * 2 + scolb;
            char* dst = (char*)Blin + it * 4096 + t * 16;
            gload16(src, dst);
        }

        // K tile (32 x 64): cols {gjA, gjB}, rows rb..rb+3; kraw once per elem
        const int gjA = j0 + 2 * c2, gjB = gjA + 1;
        const float4 cjA = c4[gjA];
        const float4 cjB = c4[gjB];
        const float sqA = cjA.x * cjA.x + cjA.y * cjA.y + cjA.z * cjA.z;
        const float sqB = cjB.x * cjB.x + cjB.y * cjB.y + cjB.z * cjB.z;
        #pragma unroll
        for (int rr = 0; rr < 4; ++rr) {
            int r = rb + rr, gi = i0 + r;
            float kA = (gi == gjA) ? 0.0f : kraw_f(rc[rr], rs[rr], cjA, sqA);
            float kB = (gi == gjB) ? 0.0f : kraw_f(rc[rr], rs[rr], cjB, sqB);
            float knA = kA * rv[rr];
            float knB = kB * rv[rr];
            float2 st = {knA, knB};
            *reinterpret_cast<float2*>(Kout + (size_t)gi * kN + gjA) = st;  // 256B/row coalesced
            __bf16 hA = (__bf16)knA, hB = (__bf16)knB;
            unsigned pk = ((unsigned)*(unsigned short*)&hB << 16) | *(unsigned short*)&hA;
            *reinterpret_cast<unsigned*>(&Alds[r][2 * c2]) = pk;
        }

        // b1: counted drain — gloads + ds_writes visible, stores stay in flight
        asm volatile("s_waitcnt vmcnt(4) lgkmcnt(0)" ::: "memory");
        __builtin_amdgcn_sched_barrier(0);
        __builtin_amdgcn_s_barrier();
        __builtin_amdgcn_sched_barrier(0);

        // MFMA: A row-tiles {0,1} x B dim-tiles {0,1}
        #pragma unroll
        for (int kk = 0; kk < 2; ++kk) {
            v8bf a0 = *reinterpret_cast<const v8bf*>(&Alds[arow][kk * 32 + koff]);
            v8bf a1 = *reinterpret_cast<const v8bf*>(&Alds[16 + arow][kk * 32 + koff]);
            const int bc = kk * 64 + koff * 2;    // logical byte col
            const char* bp0 = (const char*)Blin + (dbase + arow) * 128 + (bc ^ bswz);
            const char* bp1 = (const char*)Blin + (dbase + 16 + arow) * 128 + (bc ^ bswz);
            v8bf b0 = *reinterpret_cast<const v8bf*>(bp0);
            v8bf b1 = *reinterpret_cast<const v8bf*>(bp1);
            acc[0][0] = __builtin_amdgcn_mfma_f32_16x16x32_bf16(a0, b0, acc[0][0], 0, 0, 0);
            acc[0][1] = __builtin_amdgcn_mfma_f32_16x16x32_bf16(a0, b1, acc[0][1], 0, 0, 0);
            acc[1][0] = __builtin_amdgcn_mfma_f32_16x16x32_bf16(a1, b0, acc[1][0], 0, 0, 0);
            acc[1][1] = __builtin_amdgcn_mfma_f32_16x16x32_bf16(a1, b1, acc[1][1], 0, 0, 0);
        }

        // b2: LDS-only drain — Alds/Blin safe to overwrite next iteration
        asm volatile("s_waitcnt lgkmcnt(0)" ::: "memory");
        __builtin_amdgcn_sched_barrier(0);
        __builtin_amdgcn_s_barrier();
        __builtin_amdgcn_sched_barrier(0);
    }

    // epilogue: D frag col = lane&15 (dim), row = (lane>>4)*4 + q  [m89 proven]
    const int row = (lane >> 4) * 4;
    const int col0 = wave * 32 + (lane & 15);
    #pragma unroll
    for (int rt = 0; rt < 2; ++rt)
        #pragma unroll
        for (int dt = 0; dt < 2; ++dt)
            #pragma unroll
            for (int q = 0; q < 4; ++q)
                atomicAdd(&outp[(size_t)(i0 + rt * 16 + row + q) * kD + col0 + dt * 16],
                          acc[rt][dt][q]);
}

extern "C" void kernel_launch(void* const* d_in, const int* in_sizes, int n_in,
                              void* d_out, int out_size, void* d_ws, size_t ws_size,
                              hipStream_t stream) {
    const float* latent = (const float*)d_in[0];
    const float* coords = (const float*)d_in[1];
    const float* alpha  = (const float*)d_in[2];

    float* outp = (float*)d_out;                    // [8192][128]
    float* Kout = (float*)d_out + (size_t)kN * kD;  // [8192][8192]

    // ws layout: byte-identical to the proven footprint.
    char* ws = (char*)d_ws;
    __bf16* latT = (__bf16*)ws;                                   // 2 MiB
    float4* c4   = (float4*)(ws + 2u * 1024 * 1024);              // 128 KiB
    float*  rsum = (float*)(ws + 2u * 1024 * 1024 + 128 * 1024);  // 32 KiB

    hipMemsetAsync(outp, 0, (size_t)kN * kD * sizeof(float), stream);
    hipMemsetAsync(rsum, 0, kN * sizeof(float), stream);

    pack_k<<<dim3(kN / 256), dim3(256), 0, stream>>>(coords, alpha, c4);
    transpose_k<<<dim3(kN / 32, kD / 32), dim3(256), 0, stream>>>(latent, latT);
    rowsum_sym_k<<<dim3(NB * (NB + 1) / 2), dim3(256), 0, stream>>>(c4, rsum);
    main_k<<<dim3(kN / BM, JSPLIT), dim3(256), 0, stream>>>(c4, rsum, latT, outp, Kout);
}

// Round 18
// 120.612 us; speedup vs baseline: 1.4712x; 1.0396x over previous
//
#include <hip/hip_runtime.h>
#include <hip/hip_bf16.h>

constexpr int kN = 8192;
constexpr int kD = 128;
constexpr int BM = 32;      // rows per block in main kernel (2 MFMA row-tiles)
constexpr int BK = 64;      // j-chunk
constexpr int JSPLIT = 8;   // j-range strips (grid at 2048 blocks)
constexpr int LDB = 66;     // A-tile LDS row stride: 132B (r9-proven, conflict-free)
constexpr int TB = 64;      // rowsum tile
constexpr int NB = kN / TB; // 128

typedef __bf16 v8bf __attribute__((ext_vector_type(8)));
typedef float  v4f  __attribute__((ext_vector_type(4)));

// async global->LDS, 16B per lane (r10-proven).
__device__ __forceinline__ void gload16(const void* g, void* l) {
    __builtin_amdgcn_global_load_lds(
        (const __attribute__((address_space(1))) void*)g,
        (__attribute__((address_space(3))) void*)l, 16, 0, 0);
}

// K_raw with 3 transcendentals (round-8 proven).
__device__ __forceinline__ float kraw_f(float4 ci, float sqi, float4 cj, float sqj) {
    float d2 = sqi + sqj - 2.0f * (ci.x * cj.x + ci.y * cj.y + ci.z * cj.z);
    d2 = fmaxf(d2, 1e-12f);
    float Dd = __builtin_amdgcn_sqrtf(d2);
    float a = 0.5f * (ci.w + cj.w);
    float t = a * (-0.5f * __builtin_amdgcn_logf(d2));                // -a*log2(D)
    t = fminf(fmaxf(t, -26.575424759098897f), 9.965784284662087f);   // log2(1e-8), log2(1000)
    float K = __builtin_amdgcn_exp2f(fmaf(Dd, -0.12022458674074695f, t));
    return fminf(K, 1000.0f);  // K >= 0 always
}

// --- kernel 1: pack coords+alpha into float4; zero rsum (fused memset) -----
__global__ void pack_k(const float* __restrict__ coords, const float* __restrict__ alpha,
                       float4* __restrict__ c4, float* __restrict__ rsum) {
    int j = blockIdx.x * 256 + threadIdx.x;
    if (j < kN) {
        c4[j] = make_float4(coords[3 * j], coords[3 * j + 1], coords[3 * j + 2], alpha[j]);
        rsum[j] = 0.0f;   // consumed by rowsum_sym_k (later in stream order)
    }
}

// --- kernel 2: transpose latent -> latT bf16; zero outp (fused memset) -----
__global__ void transpose_k(const float* __restrict__ latent, __bf16* __restrict__ latT,
                            float* __restrict__ outp) {
    __shared__ float tile[32][33];
    int t = threadIdx.x;
    int tx = t & 31, ty = t >> 5;          // 32 x 8
    int j0 = blockIdx.x * 32, d0 = blockIdx.y * 32;
    #pragma unroll
    for (int i = 0; i < 32; i += 8)
        tile[ty + i][tx] = latent[(size_t)(j0 + ty + i) * kD + d0 + tx];

    // zero outp: grid (256,4) x 256 threads x 4 floats = kN*kD, bijective.
    {
        size_t base = (((size_t)blockIdx.x * 4 + blockIdx.y) * 256 + t) * 4;
        v4f z = {0.f, 0.f, 0.f, 0.f};
        *reinterpret_cast<v4f*>(outp + base) = z;   // consumed by main_k later
    }
    __syncthreads();
    #pragma unroll
    for (int i = 0; i < 32; i += 8)
        latT[(size_t)(d0 + ty + i) * kN + j0 + tx] = (__bf16)tile[tx][ty + i];
}

// --- kernel 3: SYMMETRIC row sums (round-11 proven) ------------------------
__global__ __launch_bounds__(256) void rowsum_sym_k(const float4* __restrict__ c4,
                                                    float* __restrict__ rsum) {
    __shared__ float4 rc4[TB];
    __shared__ float  rsq[TB];
    __shared__ float  rowbuf[TB][TB + 1];   // 16.25 KB

    // decode triangular pair (bi <= bj) from linear block index
    int L = blockIdx.x;
    int bi = (int)((2 * NB + 1 - sqrtf((float)((2 * NB + 1) * (2 * NB + 1) - 8 * L))) * 0.5f);
    #pragma unroll
    for (int f = 0; f < 2; ++f) {
        int s0 = bi * NB - bi * (bi - 1) / 2;
        int s1 = (bi + 1) * NB - (bi + 1) * bi / 2;
        if (L >= s1) ++bi;
        else if (L < s0) --bi;
    }
    int sbi = bi * NB - bi * (bi - 1) / 2;
    int bj = bi + (L - sbi);
    bool diag = (bi == bj);

    const int t = threadIdx.x;
    const int l = t & 63;
    const int w = t >> 6;

    if (t < TB) {
        float4 ci = c4[bi * TB + t];
        rc4[t] = ci;
        rsq[t] = ci.x * ci.x + ci.y * ci.y + ci.z * ci.z;
    }
    __syncthreads();

    float4 cj = c4[bj * TB + l];
    float sqj = cj.x * cj.x + cj.y * cj.y + cj.z * cj.z;

    float colacc = 0.f;
    #pragma unroll
    for (int rr = 0; rr < 16; ++rr) {
        int r = w * 16 + rr;
        float k = kraw_f(rc4[r], rsq[r], cj, sqj);
        if (diag && r == l) k = 0.f;
        colacc += k;
        rowbuf[r][l] = k;
    }
    __syncthreads();

    // row sums: thread t -> row r = t>>2, quarter q = t&3 (adjacent lanes)
    {
        int r = t >> 2, q = t & 3;
        float p = 0.f;
        #pragma unroll
        for (int m = 0; m < 16; ++m) p += rowbuf[r][q * 16 + m];
        p += __shfl_xor(p, 1, 64);
        p += __shfl_xor(p, 2, 64);
        if (q == 0) atomicAdd(&rsum[bi * TB + r], p);
    }
    if (!diag) atomicAdd(&rsum[bj * TB + l], colacc);
}

// --- kernel 4: fused K write + MFMA GEMM (round-11 EXACT, 123.8 µs proven) -
__global__ __launch_bounds__(256, 2) void main_k(
    const float4* __restrict__ c4, const float* __restrict__ rsum,
    const __bf16* __restrict__ latT, float* __restrict__ outp, float* __restrict__ Kout) {

    __shared__ __bf16 Alds[BM][LDB];    // 4.2 KB, normalized K tile
    __shared__ __bf16 Blin[kD * BK];    // 16 KB, swizzled physical layout
    __shared__ float4 c4row[BM];
    __shared__ float  sqrow[BM];
    __shared__ float  invrow[BM];

    const int t = threadIdx.x;
    const int i0 = blockIdx.x * BM;
    const int jstrip = blockIdx.y * (kN / JSPLIT);

    if (t < BM) {
        float4 ci = c4[i0 + t];
        c4row[t] = ci;
        sqrow[t] = ci.x * ci.x + ci.y * ci.y + ci.z * ci.z;
        invrow[t] = 1.0f / (rsum[i0 + t] + 1e-8f);
    }
    __syncthreads();

    const int lane = t & 63;
    const int wave = t >> 6;

    // K-tile compute mapping: col pair {2*c2, 2*c2+1}, rows rb..rb+3
    const int c2 = t & 31;
    const int rb = (t >> 5) * 4;

    // hoist this thread's 4 fixed rows into registers (r11-proven)
    float4 rc[4]; float rs[4], rv[4];
    #pragma unroll
    for (int rr = 0; rr < 4; ++rr) {
        rc[rr] = c4row[rb + rr];
        rs[rr] = sqrow[rb + rr];
        rv[rr] = invrow[rb + rr];
    }

    // MFMA fragment addressing (r9/r10-proven)
    const int arow = lane & 15;
    const int koff = (lane >> 4) * 8;          // elements
    const int dbase = wave * 32;
    const int bswz = ((dbase + arow) & 7) << 4; // source/read XOR (involution)

    // staging: dest byte = it*4096 + t*16 -> (row = it*32 + t/8, col-byte =
    // (t&7)*16); source col-byte pre-swizzled by ^((row&7)<<4)
    const int srow = t >> 3;
    const int scolb = ((t & 7) ^ (srow & 7)) << 4;

    v4f acc[2][2];
    #pragma unroll
    for (int rt = 0; rt < 2; ++rt)
        #pragma unroll
        for (int dt = 0; dt < 2; ++dt) acc[rt][dt] = (v4f){0.f, 0.f, 0.f, 0.f};

    for (int cb = 0; cb < kN / JSPLIT / BK; ++cb) {
        const int j0 = jstrip + cb * BK;

        // issue async B staging first (flies under the kraw compute)
        #pragma unroll
        for (int it = 0; it < 4; ++it) {
            int row = it * 32 + srow;
            const char* src = (const char*)latT + ((size_t)row * kN + j0) * 2 + scolb;
            char* dst = (char*)Blin + it * 4096 + t * 16;
            gload16(src, dst);
        }

        // K tile (32 x 64): cols {gjA, gjB}, rows rb..rb+3; kraw once per elem
        const int gjA = j0 + 2 * c2, gjB = gjA + 1;
        const float4 cjA = c4[gjA];
        const float4 cjB = c4[gjB];
        const float sqA = cjA.x * cjA.x + cjA.y * cjA.y + cjA.z * cjA.z;
        const float sqB = cjB.x * cjB.x + cjB.y * cjB.y + cjB.z * cjB.z;
        #pragma unroll
        for (int rr = 0; rr < 4; ++rr) {
            int r = rb + rr, gi = i0 + r;
            float kA = (gi == gjA) ? 0.0f : kraw_f(rc[rr], rs[rr], cjA, sqA);
            float kB = (gi == gjB) ? 0.0f : kraw_f(rc[rr], rs[rr], cjB, sqB);
            float knA = kA * rv[rr];
            float knB = kB * rv[rr];
            float2 st = {knA, knB};
            *reinterpret_cast<float2*>(Kout + (size_t)gi * kN + gjA) = st;  // 256B/row coalesced
            __bf16 hA = (__bf16)knA, hB = (__bf16)knB;
            unsigned pk = ((unsigned)*(unsigned short*)&hB << 16) | *(unsigned short*)&hA;
            *reinterpret_cast<unsigned*>(&Alds[r][2 * c2]) = pk;
        }
        __syncthreads();

        // MFMA: A row-tiles {0,1} x B dim-tiles {0,1}
        #pragma unroll
        for (int kk = 0; kk < 2; ++kk) {
            v8bf a0 = *reinterpret_cast<const v8bf*>(&Alds[arow][kk * 32 + koff]);
            v8bf a1 = *reinterpret_cast<const v8bf*>(&Alds[16 + arow][kk * 32 + koff]);
            const int bc = kk * 64 + koff * 2;    // logical byte col
            const char* bp0 = (const char*)Blin + (dbase + arow) * 128 + (bc ^ bswz);
            const char* bp1 = (const char*)Blin + (dbase + 16 + arow) * 128 + (bc ^ bswz);
            v8bf b0 = *reinterpret_cast<const v8bf*>(bp0);
            v8bf b1 = *reinterpret_cast<const v8bf*>(bp1);
            acc[0][0] = __builtin_amdgcn_mfma_f32_16x16x32_bf16(a0, b0, acc[0][0], 0, 0, 0);
            acc[0][1] = __builtin_amdgcn_mfma_f32_16x16x32_bf16(a0, b1, acc[0][1], 0, 0, 0);
            acc[1][0] = __builtin_amdgcn_mfma_f32_16x16x32_bf16(a1, b0, acc[1][0], 0, 0, 0);
            acc[1][1] = __builtin_amdgcn_mfma_f32_16x16x32_bf16(a1, b1, acc[1][1], 0, 0, 0);
        }
        __syncthreads();
    }

    // epilogue: D frag col = lane&15 (dim), row = (lane>>4)*4 + q  [m89 proven]
    const int row = (lane >> 4) * 4;
    const int col0 = wave * 32 + (lane & 15);
    #pragma unroll
    for (int rt = 0; rt < 2; ++rt)
        #pragma unroll
        for (int dt = 0; dt < 2; ++dt)
            #pragma unroll
            for (int q = 0; q < 4; ++q)
                atomicAdd(&outp[(size_t)(i0 + rt * 16 + row + q) * kD + col0 + dt * 16],
                          acc[rt][dt][q]);
}

extern "C" void kernel_launch(void* const* d_in, const int* in_sizes, int n_in,
                              void* d_out, int out_size, void* d_ws, size_t ws_size,
                              hipStream_t stream) {
    const float* latent = (const float*)d_in[0];
    const float* coords = (const float*)d_in[1];
    const float* alpha  = (const float*)d_in[2];

    float* outp = (float*)d_out;                    // [8192][128]
    float* Kout = (float*)d_out + (size_t)kN * kD;  // [8192][8192]

    // ws layout: byte-identical to the proven footprint.
    char* ws = (char*)d_ws;
    __bf16* latT = (__bf16*)ws;                                   // 2 MiB
    float4* c4   = (float4*)(ws + 2u * 1024 * 1024);              // 128 KiB
    float*  rsum = (float*)(ws + 2u * 1024 * 1024 + 128 * 1024);  // 32 KiB

    // memsets folded into pack_k (rsum) and transpose_k (outp):
    // both complete before their consumers via stream ordering.
    pack_k<<<dim3(kN / 256), dim3(256), 0, stream>>>(coords, alpha, c4, rsum);
    transpose_k<<<dim3(kN / 32, kD / 32), dim3(256), 0, stream>>>(latent, latT, outp);
    rowsum_sym_k<<<dim3(NB * (NB + 1) / 2), dim3(256), 0, stream>>>(c4, rsum);
    main_k<<<dim3(kN / BM, JSPLIT), dim3(256), 0, stream>>>(c4, rsum, latT, outp, Kout);
}

// Round 19
// 117.086 us; speedup vs baseline: 1.5155x; 1.0301x over previous
//
#include <hip/hip_runtime.h>
#include <hip/hip_bf16.h>

constexpr int kN = 8192;
constexpr int kD = 128;
constexpr int BM = 32;      // rows per block in main kernel (2 MFMA row-tiles)
constexpr int BK = 64;      // j-chunk
constexpr int JSPLIT = 8;   // j-range strips (grid at 2048 blocks)
constexpr int LDB = 72;     // A-tile LDS row stride: 144B = 16B-aligned rows
                            // (b128-clean) AND 2-way banks only (free, m136).
                            // r11's 66 (132B) left odd rows 4B-aligned -> split reads.
constexpr int TB = 64;      // rowsum tile
constexpr int NB = kN / TB; // 128

typedef __bf16 v8bf __attribute__((ext_vector_type(8)));
typedef float  v4f  __attribute__((ext_vector_type(4)));

// async global->LDS, 16B per lane (r10-proven).
__device__ __forceinline__ void gload16(const void* g, void* l) {
    __builtin_amdgcn_global_load_lds(
        (const __attribute__((address_space(1))) void*)g,
        (__attribute__((address_space(3))) void*)l, 16, 0, 0);
}

// K_raw with 3 transcendentals (round-8 proven).
__device__ __forceinline__ float kraw_f(float4 ci, float sqi, float4 cj, float sqj) {
    float d2 = sqi + sqj - 2.0f * (ci.x * cj.x + ci.y * cj.y + ci.z * cj.z);
    d2 = fmaxf(d2, 1e-12f);
    float Dd = __builtin_amdgcn_sqrtf(d2);
    float a = 0.5f * (ci.w + cj.w);
    float t = a * (-0.5f * __builtin_amdgcn_logf(d2));                // -a*log2(D)
    t = fminf(fmaxf(t, -26.575424759098897f), 9.965784284662087f);   // log2(1e-8), log2(1000)
    float K = __builtin_amdgcn_exp2f(fmaf(Dd, -0.12022458674074695f, t));
    return fminf(K, 1000.0f);  // K >= 0 always
}

// --- kernel 1: pack coords+alpha into float4; zero rsum (r18 proven) -------
__global__ void pack_k(const float* __restrict__ coords, const float* __restrict__ alpha,
                       float4* __restrict__ c4, float* __restrict__ rsum) {
    int j = blockIdx.x * 256 + threadIdx.x;
    if (j < kN) {
        c4[j] = make_float4(coords[3 * j], coords[3 * j + 1], coords[3 * j + 2], alpha[j]);
        rsum[j] = 0.0f;   // consumed by rowsum_sym_k (later in stream order)
    }
}

// --- kernel 2: transpose latent -> latT bf16; zero outp (r18 proven) -------
__global__ void transpose_k(const float* __restrict__ latent, __bf16* __restrict__ latT,
                            float* __restrict__ outp) {
    __shared__ float tile[32][33];
    int t = threadIdx.x;
    int tx = t & 31, ty = t >> 5;          // 32 x 8
    int j0 = blockIdx.x * 32, d0 = blockIdx.y * 32;
    #pragma unroll
    for (int i = 0; i < 32; i += 8)
        tile[ty + i][tx] = latent[(size_t)(j0 + ty + i) * kD + d0 + tx];

    // zero outp: grid (256,4) x 256 threads x 4 floats = kN*kD, bijective.
    {
        size_t base = (((size_t)blockIdx.x * 4 + blockIdx.y) * 256 + t) * 4;
        v4f z = {0.f, 0.f, 0.f, 0.f};
        *reinterpret_cast<v4f*>(outp + base) = z;   // consumed by main_k later
    }
    __syncthreads();
    #pragma unroll
    for (int i = 0; i < 32; i += 8)
        latT[(size_t)(d0 + ty + i) * kN + j0 + tx] = (__bf16)tile[tx][ty + i];
}

// --- kernel 3: SYMMETRIC row sums (round-11 proven) ------------------------
__global__ __launch_bounds__(256) void rowsum_sym_k(const float4* __restrict__ c4,
                                                    float* __restrict__ rsum) {
    __shared__ float4 rc4[TB];
    __shared__ float  rsq[TB];
    __shared__ float  rowbuf[TB][TB + 1];   // 16.25 KB

    // decode triangular pair (bi <= bj) from linear block index
    int L = blockIdx.x;
    int bi = (int)((2 * NB + 1 - sqrtf((float)((2 * NB + 1) * (2 * NB + 1) - 8 * L))) * 0.5f);
    #pragma unroll
    for (int f = 0; f < 2; ++f) {
        int s0 = bi * NB - bi * (bi - 1) / 2;
        int s1 = (bi + 1) * NB - (bi + 1) * bi / 2;
        if (L >= s1) ++bi;
        else if (L < s0) --bi;
    }
    int sbi = bi * NB - bi * (bi - 1) / 2;
    int bj = bi + (L - sbi);
    bool diag = (bi == bj);

    const int t = threadIdx.x;
    const int l = t & 63;
    const int w = t >> 6;

    if (t < TB) {
        float4 ci = c4[bi * TB + t];
        rc4[t] = ci;
        rsq[t] = ci.x * ci.x + ci.y * ci.y + ci.z * ci.z;
    }
    __syncthreads();

    float4 cj = c4[bj * TB + l];
    float sqj = cj.x * cj.x + cj.y * cj.y + cj.z * cj.z;

    float colacc = 0.f;
    #pragma unroll
    for (int rr = 0; rr < 16; ++rr) {
        int r = w * 16 + rr;
        float k = kraw_f(rc4[r], rsq[r], cj, sqj);
        if (diag && r == l) k = 0.f;
        colacc += k;
        rowbuf[r][l] = k;
    }
    __syncthreads();

    // row sums: thread t -> row r = t>>2, quarter q = t&3 (adjacent lanes)
    {
        int r = t >> 2, q = t & 3;
        float p = 0.f;
        #pragma unroll
        for (int m = 0; m < 16; ++m) p += rowbuf[r][q * 16 + m];
        p += __shfl_xor(p, 1, 64);
        p += __shfl_xor(p, 2, 64);
        if (q == 0) atomicAdd(&rsum[bi * TB + r], p);
    }
    if (!diag) atomicAdd(&rsum[bj * TB + l], colacc);
}

// --- kernel 4: fused K write + MFMA GEMM (round-11 EXACT, LDB=72) ----------
__global__ __launch_bounds__(256, 2) void main_k(
    const float4* __restrict__ c4, const float* __restrict__ rsum,
    const __bf16* __restrict__ latT, float* __restrict__ outp, float* __restrict__ Kout) {

    __shared__ __bf16 Alds[BM][LDB];    // 4.6 KB, normalized K tile
    __shared__ __bf16 Blin[kD * BK];    // 16 KB, swizzled physical layout
    __shared__ float4 c4row[BM];
    __shared__ float  sqrow[BM];
    __shared__ float  invrow[BM];

    const int t = threadIdx.x;
    const int i0 = blockIdx.x * BM;
    const int jstrip = blockIdx.y * (kN / JSPLIT);

    if (t < BM) {
        float4 ci = c4[i0 + t];
        c4row[t] = ci;
        sqrow[t] = ci.x * ci.x + ci.y * ci.y + ci.z * ci.z;
        invrow[t] = 1.0f / (rsum[i0 + t] + 1e-8f);
    }
    __syncthreads();

    const int lane = t & 63;
    const int wave = t >> 6;

    // K-tile compute mapping: col pair {2*c2, 2*c2+1}, rows rb..rb+3
    const int c2 = t & 31;
    const int rb = (t >> 5) * 4;

    // hoist this thread's 4 fixed rows into registers (r11-proven)
    float4 rc[4]; float rs[4], rv[4];
    #pragma unroll
    for (int rr = 0; rr < 4; ++rr) {
        rc[rr] = c4row[rb + rr];
        rs[rr] = sqrow[rb + rr];
        rv[rr] = invrow[rb + rr];
    }

    // MFMA fragment addressing (r9/r10-proven)
    const int arow = lane & 15;
    const int koff = (lane >> 4) * 8;          // elements
    const int dbase = wave * 32;
    const int bswz = ((dbase + arow) & 7) << 4; // source/read XOR (involution)

    // staging: dest byte = it*4096 + t*16 -> (row = it*32 + t/8, col-byte =
    // (t&7)*16); source col-byte pre-swizzled by ^((row&7)<<4)
    const int srow = t >> 3;
    const int scolb = ((t & 7) ^ (srow & 7)) << 4;

    v4f acc[2][2];
    #pragma unroll
    for (int rt = 0; rt < 2; ++rt)
        #pragma unroll
        for (int dt = 0; dt < 2; ++dt) acc[rt][dt] = (v4f){0.f, 0.f, 0.f, 0.f};

    for (int cb = 0; cb < kN / JSPLIT / BK; ++cb) {
        const int j0 = jstrip + cb * BK;

        // issue async B staging first (flies under the kraw compute)
        #pragma unroll
        for (int it = 0; it < 4; ++it) {
            int row = it * 32 + srow;
            const char* src = (const char*)latT + ((size_t)row * kN + j0) * 2 + scolb;
            char* dst = (char*)Blin + it * 4096 + t * 16;
            gload16(src, dst);
        }

        // K tile (32 x 64): cols {gjA, gjB}, rows rb..rb+3; kraw once per elem
        const int gjA = j0 + 2 * c2, gjB = gjA + 1;
        const float4 cjA = c4[gjA];
        const float4 cjB = c4[gjB];
        const float sqA = cjA.x * cjA.x + cjA.y * cjA.y + cjA.z * cjA.z;
        const float sqB = cjB.x * cjB.x + cjB.y * cjB.y + cjB.z * cjB.z;
        #pragma unroll
        for (int rr = 0; rr < 4; ++rr) {
            int r = rb + rr, gi = i0 + r;
            float kA = (gi == gjA) ? 0.0f : kraw_f(rc[rr], rs[rr], cjA, sqA);
            float kB = (gi == gjB) ? 0.0f : kraw_f(rc[rr], rs[rr], cjB, sqB);
            float knA = kA * rv[rr];
            float knB = kB * rv[rr];
            float2 st = {knA, knB};
            *reinterpret_cast<float2*>(Kout + (size_t)gi * kN + gjA) = st;  // 256B/row coalesced
            __bf16 hA = (__bf16)knA, hB = (__bf16)knB;
            unsigned pk = ((unsigned)*(unsigned short*)&hB << 16) | *(unsigned short*)&hA;
            *reinterpret_cast<unsigned*>(&Alds[r][2 * c2]) = pk;
        }
        __syncthreads();

        // MFMA: A row-tiles {0,1} x B dim-tiles {0,1}
        #pragma unroll
        for (int kk = 0; kk < 2; ++kk) {
            v8bf a0 = *reinterpret_cast<const v8bf*>(&Alds[arow][kk * 32 + koff]);
            v8bf a1 = *reinterpret_cast<const v8bf*>(&Alds[16 + arow][kk * 32 + koff]);
            const int bc = kk * 64 + koff * 2;    // logical byte col
            const char* bp0 = (const char*)Blin + (dbase + arow) * 128 + (bc ^ bswz);
            const char* bp1 = (const char*)Blin + (dbase + 16 + arow) * 128 + (bc ^ bswz);
            v8bf b0 = *reinterpret_cast<const v8bf*>(bp0);
            v8bf b1 = *reinterpret_cast<const v8bf*>(bp1);
            acc[0][0] = __builtin_amdgcn_mfma_f32_16x16x32_bf16(a0, b0, acc[0][0], 0, 0, 0);
            acc[0][1] = __builtin_amdgcn_mfma_f32_16x16x32_bf16(a0, b1, acc[0][1], 0, 0, 0);
            acc[1][0] = __builtin_amdgcn_mfma_f32_16x16x32_bf16(a1, b0, acc[1][0], 0, 0, 0);
            acc[1][1] = __builtin_amdgcn_mfma_f32_16x16x32_bf16(a1, b1, acc[1][1], 0, 0, 0);
        }
        __syncthreads();
    }

    // epilogue: D frag col = lane&15 (dim), row = (lane>>4)*4 + q  [m89 proven]
    const int row = (lane >> 4) * 4;
    const int col0 = wave * 32 + (lane & 15);
    #pragma unroll
    for (int rt = 0; rt < 2; ++rt)
        #pragma unroll
        for (int dt = 0; dt < 2; ++dt)
            #pragma unroll
            for (int q = 0; q < 4; ++q)
                atomicAdd(&outp[(size_t)(i0 + rt * 16 + row + q) * kD + col0 + dt * 16],
                          acc[rt][dt][q]);
}

extern "C" void kernel_launch(void* const* d_in, const int* in_sizes, int n_in,
                              void* d_out, int out_size, void* d_ws, size_t ws_size,
                              hipStream_t stream) {
    const float* latent = (const float*)d_in[0];
    const float* coords = (const float*)d_in[1];
    const float* alpha  = (const float*)d_in[2];

    float* outp = (float*)d_out;                    // [8192][128]
    float* Kout = (float*)d_out + (size_t)kN * kD;  // [8192][8192]

    // ws layout: byte-identical to the proven footprint.
    char* ws = (char*)d_ws;
    __bf16* latT = (__bf16*)ws;                                   // 2 MiB
    float4* c4   = (float4*)(ws + 2u * 1024 * 1024);              // 128 KiB
    float*  rsum = (float*)(ws + 2u * 1024 * 1024 + 128 * 1024);  // 32 KiB

    pack_k<<<dim3(kN / 256), dim3(256), 0, stream>>>(coords, alpha, c4, rsum);
    transpose_k<<<dim3(kN / 32, kD / 32), dim3(256), 0, stream>>>(latent, latT, outp);
    rowsum_sym_k<<<dim3(NB * (NB + 1) / 2), dim3(256), 0, stream>>>(c4, rsum);
    main_k<<<dim3(kN / BM, JSPLIT), dim3(256), 0, stream>>>(c4, rsum, latT, outp, Kout);
}